// Round 4
// baseline (849.574 us; speedup 1.0000x reference)
//
#include <hip/hip_runtime.h>
#include <math.h>

// Problem constants (fixed by setup_inputs)
#define NB 4
#define NS 4096
#define NL 8192
#define ND 256
#define NP2 128
#define NK 16

// ---------------------------------------------------------------------------
// Reference-matching fp32 distance metric (XLA/BLAS k=2 GEMM model):
//   q2 = fl(qx^2) + fl(qy^2)            (fused mul+reduce: no FMA)
//   m2 = fl(mx^2) + fl(my^2)
//   dot = fma(qy, my, fl(qx*mx))        (GEMM k-loop: acc = fma(a,b,acc))
//   d2 = fl(fl(q2 + m2) - 2*dot)        (elementwise fusion: no contraction)
// 2*dot is exact. contract(off) everywhere else so the compiler cannot fuse
// the final subtract into an FMA. Order flips at 1-ulp near-ties are fatal
// (threshold 4.88e-4 << wrong-row magnitude ~2e-2), so these bits matter.
// ---------------------------------------------------------------------------
__device__ __forceinline__ float sum_sq_np(float x, float y) {
#pragma clang fp contract(off)
  return x * x + y * y;
}

__device__ __forceinline__ float dist2_ref(float q2, float m2, float qx, float qy,
                                           float mx, float my) {
#pragma clang fp contract(off)
  float dot = __builtin_fmaf(qy, my, qx * mx);
  float s = q2 + m2;
  return s - 2.0f * dot;
}

// float -> order-preserving uint (ascending float => ascending uint)
__device__ __forceinline__ unsigned f32ord(float f) {
  unsigned u = __float_as_uint(f);
  return u ^ ((unsigned)((int)u >> 31) | 0x80000000u);
}

// ---------------------------------------------------------------------------
// Kernel 1: rows of posemb(coor) -> relu(pe@W1+b1)@W2+b2 (+ optional memory)
// 16 rows per block, 128 threads; thread owns output cols (tid, tid+128).
// pe and h staged transposed in LDS ([k][row]) so inner loops are
// broadcast LDS reads + coalesced weight loads + register-tile FMAs.
// ---------------------------------------------------------------------------
struct MlpSmem {
  float pe[NP2][16];  // 8 KB
  float h[ND][16];    // 16 KB
};

__device__ __forceinline__ void fma16(float* acc, float wt, const float4& p0,
                                      const float4& p1, const float4& p2,
                                      const float4& p3) {
  acc[0] = fmaf(p0.x, wt, acc[0]);   acc[1] = fmaf(p0.y, wt, acc[1]);
  acc[2] = fmaf(p0.z, wt, acc[2]);   acc[3] = fmaf(p0.w, wt, acc[3]);
  acc[4] = fmaf(p1.x, wt, acc[4]);   acc[5] = fmaf(p1.y, wt, acc[5]);
  acc[6] = fmaf(p1.z, wt, acc[6]);   acc[7] = fmaf(p1.w, wt, acc[7]);
  acc[8] = fmaf(p2.x, wt, acc[8]);   acc[9] = fmaf(p2.y, wt, acc[9]);
  acc[10] = fmaf(p2.z, wt, acc[10]); acc[11] = fmaf(p2.w, wt, acc[11]);
  acc[12] = fmaf(p3.x, wt, acc[12]); acc[13] = fmaf(p3.y, wt, acc[13]);
  acc[14] = fmaf(p3.z, wt, acc[14]); acc[15] = fmaf(p3.w, wt, acc[15]);
}

__global__ __launch_bounds__(128) void mlp_kernel(
    const float* __restrict__ coor, const float* __restrict__ W1,
    const float* __restrict__ b1, const float* __restrict__ W2,
    const float* __restrict__ b2, const float* __restrict__ addmem,
    float* __restrict__ out) {
  __shared__ MlpSmem sm;
  const int tid = threadIdx.x;
  const int row0 = blockIdx.x * 16;

  // ---- phase 1: PETR 2D sine embedding, transposed into LDS ----
  // pe[2j + 64*part][r] = sin(c * 2pi * 10000^(-j/32)), pe[2j+1+...] = cos(...)
  // part 0 = y (coor[...,1]) first, then x (coor[...,0]).
#pragma unroll
  for (int it = 0; it < 8; ++it) {
    int e = tid + it * 128;     // 0..1023 = 16 rows * 2 parts * 32 j
    int r = e >> 6;
    int rem = e & 63;
    int part = rem >> 5;        // 0 -> y, 1 -> x
    int j = rem & 31;
    float c = coor[(size_t)(row0 + r) * 2 + (part ^ 1)];
    float inv_t = exp2f((float)j * -0.4152410118609718f);  // 10000^(-j/32)
    float arg = c * 6.2831853071795864f * inv_t;
    float sv, cv;
    sincosf(arg, &sv, &cv);
    int k0 = part * 64 + 2 * j;
    sm.pe[k0][r] = sv;
    sm.pe[k0 + 1][r] = cv;
  }
  __syncthreads();

  // ---- phase 2: hidden = relu(pe @ W1 + b1) ----
  float acc0[16], acc1[16];
  {
    float bb0 = b1[tid], bb1 = b1[tid + 128];
#pragma unroll
    for (int r = 0; r < 16; ++r) { acc0[r] = bb0; acc1[r] = bb1; }
  }
#pragma unroll 2
  for (int k = 0; k < NP2; ++k) {
    float w0 = W1[(size_t)k * ND + tid];
    float w1 = W1[(size_t)k * ND + 128 + tid];
    float4 p0 = *(const float4*)&sm.pe[k][0];
    float4 p1 = *(const float4*)&sm.pe[k][4];
    float4 p2 = *(const float4*)&sm.pe[k][8];
    float4 p3 = *(const float4*)&sm.pe[k][12];
    fma16(acc0, w0, p0, p1, p2, p3);
    fma16(acc1, w1, p0, p1, p2, p3);
  }
#pragma unroll
  for (int r = 0; r < 16; ++r) {
    sm.h[tid][r] = fmaxf(acc0[r], 0.0f);
    sm.h[tid + 128][r] = fmaxf(acc1[r], 0.0f);
  }
  __syncthreads();

  // ---- phase 3: out = h @ W2 + b2 (+ memory) ----
  {
    float bb0 = b2[tid], bb1 = b2[tid + 128];
#pragma unroll
    for (int r = 0; r < 16; ++r) { acc0[r] = bb0; acc1[r] = bb1; }
  }
#pragma unroll 2
  for (int k = 0; k < ND; ++k) {
    float w0 = W2[(size_t)k * ND + tid];
    float w1 = W2[(size_t)k * ND + 128 + tid];
    float4 h0 = *(const float4*)&sm.h[k][0];
    float4 h1 = *(const float4*)&sm.h[k][4];
    float4 h2 = *(const float4*)&sm.h[k][8];
    float4 h3 = *(const float4*)&sm.h[k][12];
    fma16(acc0, w0, h0, h1, h2, h3);
    fma16(acc1, w1, h0, h1, h2, h3);
  }
#pragma unroll
  for (int r = 0; r < 16; ++r) {
    size_t g = (size_t)(row0 + r);
    float v0 = acc0[r], v1 = acc1[r];
    if (addmem) {
      v0 += addmem[g * ND + tid];
      v1 += addmem[g * ND + 128 + tid];
    }
    out[g * ND + tid] = v0;
    out[g * ND + 128 + tid] = v1;
  }
}

// ---------------------------------------------------------------------------
// Kernel 2: exact top-16 nearest neighbors per query under dist2_ref fp32
// bits (ties by lower index, matching XLA top_k). 4 waves/block, one query
// per wave:
//   1) scan (dist2_ref) -> per-lane min; tau = 16th-smallest of the 64 lane
//      minima (lane minima are a subset of all d2, so the 16th order stat
//      upper-bounds d2_(16); equal minima knocked out together only raise it).
//   2) rescan, ballot-compact hits (d2 <= tau) into LDS (~17-40 cands).
//   3) 16 rounds of u64 (ord(d2)<<32 | idx) butterfly-min.
// Same metric in all phases => superset guarantee needs no slack.
// ---------------------------------------------------------------------------
#define TTILE 2048

__global__ __launch_bounds__(256) void topk_kernel(
    const float* __restrict__ q_coor, const float* __restrict__ mem_coor,
    int* __restrict__ idx_out) {
  __shared__ float2 tc[TTILE];                 // 16 KB
  __shared__ float tm2[TTILE];                 // 8 KB
  __shared__ unsigned long long cand[4][256];  // 8 KB
  __shared__ int cnt[4];

  const int tid = threadIdx.x;
  const int wv = tid >> 6;
  const int lane = tid & 63;
  const int qi = blockIdx.x * 4 + wv;  // b*S + s  (4 | NS, so b uniform/block)
  const int b = qi >> 12;              // / NS

  const float qx = q_coor[(size_t)qi * 2 + 0];
  const float qy = q_coor[(size_t)qi * 2 + 1];
  const float q2 = sum_sq_np(qx, qy);
  const float2* mc = (const float2*)mem_coor + (size_t)b * NL;

  // ---- phase 1: per-lane minima under the reference metric ----
  float lmin = __builtin_inff();
  for (int t = 0; t < NL / TTILE; ++t) {
    __syncthreads();
    for (int i = tid; i < TTILE; i += 256) {
      float2 v = mc[t * TTILE + i];
      tc[i] = v;
      tm2[i] = sum_sq_np(v.x, v.y);
    }
    __syncthreads();
#pragma unroll 4
    for (int it = 0; it < TTILE / 64; ++it) {
      float2 c = tc[it * 64 + lane];
      float d2 = dist2_ref(q2, tm2[it * 64 + lane], qx, qy, c.x, c.y);
      lmin = fminf(lmin, d2);
    }
  }

  // ---- tau = 16th smallest of the 64 lane minima ----
  float tau;
  {
    float cur = lmin;
    for (int r = 0; r < NK; ++r) {
      float m = cur;
#pragma unroll
      for (int o = 1; o < 64; o <<= 1) m = fminf(m, __shfl_xor(m, o, 64));
      tau = m;
      if (cur == m) cur = __builtin_inff();
    }
  }

  // ---- phase 2: compact candidates with d2 <= tau ----
  if (lane == 0) cnt[wv] = 0;
  for (int t = 0; t < NL / TTILE; ++t) {
    __syncthreads();
    for (int i = tid; i < TTILE; i += 256) {
      float2 v = mc[t * TTILE + i];
      tc[i] = v;
      tm2[i] = sum_sq_np(v.x, v.y);
    }
    __syncthreads();
#pragma unroll 4
    for (int it = 0; it < TTILE / 64; ++it) {
      int p = it * 64 + lane;
      float2 c = tc[p];
      float d2 = dist2_ref(q2, tm2[p], qx, qy, c.x, c.y);
      bool hit = (d2 <= tau);
      unsigned long long mask = __ballot(hit);
      if (mask) {  // wave-uniform branch; usually false
        int base = cnt[wv];
        if (hit) {
          int pos = base + (int)__popcll(mask & ((1ull << lane) - 1ull));
          if (pos < 256) {
            cand[wv][pos] = ((unsigned long long)f32ord(d2) << 32) |
                            (unsigned)(t * TTILE + p);
          }
        }
        if (lane == 0) cnt[wv] = base + (int)__popcll(mask);
      }
    }
  }

  // ---- phase 3: 16 rounds of wave-wide u64 min (d2 asc, ties idx asc) ----
  int N = cnt[wv];
  if (N > 256) N = 256;
  unsigned long long myc[4];
#pragma unroll
  for (int j = 0; j < 4; ++j) {
    int p = lane + j * 64;
    myc[j] = (p < N) ? cand[wv][p] : ~0ull;
  }
#pragma unroll 1
  for (int r = 0; r < NK; ++r) {
    unsigned long long m01 = myc[0] < myc[1] ? myc[0] : myc[1];
    unsigned long long m23 = myc[2] < myc[3] ? myc[2] : myc[3];
    unsigned long long m = m01 < m23 ? m01 : m23;
#pragma unroll
    for (int o = 1; o < 64; o <<= 1) {
      unsigned long long other = __shfl_xor(m, o, 64);
      if (other < m) m = other;
    }
    if (lane == 0) idx_out[(size_t)qi * NK + r] = (int)(unsigned)(m & 0xffffffffull);
#pragma unroll
    for (int j = 0; j < 4; ++j)
      if (myc[j] == m) myc[j] = ~0ull;
  }
}

// ---------------------------------------------------------------------------
// Kernel 3: gather + per-(b,s,k) softmax over D + scale by memory.
// One wave per (b,s); 4 features per lane; wave shuffle reductions.
// ---------------------------------------------------------------------------
__global__ __launch_bounds__(256) void attn_kernel(
    const float* __restrict__ query, const float* __restrict__ kv_pe,
    const float* __restrict__ memory, const int* __restrict__ idx,
    float* __restrict__ out) {
  const int tid = threadIdx.x;
  const int wv = tid >> 6;
  const int lane = tid & 63;
  const int qi = blockIdx.x * 4 + wv;  // b*S + s
  const int b = qi >> 12;

  float4 q4 = *(const float4*)(query + (size_t)qi * ND + lane * 4);

#pragma unroll 1
  for (int k = 0; k < NK; ++k) {
    int l = idx[(size_t)qi * NK + k];
    size_t base = ((size_t)b * NL + l) * ND + (size_t)lane * 4;
    float4 kv = *(const float4*)(kv_pe + base);
    // prod = query * kv_pe / sqrt(256); /16 is exact so *0.0625f matches bits
    float p0 = q4.x * kv.x * 0.0625f;
    float p1 = q4.y * kv.y * 0.0625f;
    float p2 = q4.z * kv.z * 0.0625f;
    float p3 = q4.w * kv.w * 0.0625f;
    float mx = fmaxf(fmaxf(p0, p1), fmaxf(p2, p3));
#pragma unroll
    for (int o = 1; o < 64; o <<= 1) mx = fmaxf(mx, __shfl_xor(mx, o, 64));
    float e0 = expf(p0 - mx);
    float e1 = expf(p1 - mx);
    float e2 = expf(p2 - mx);
    float e3 = expf(p3 - mx);
    float s = (e0 + e1) + (e2 + e3);
#pragma unroll
    for (int o = 1; o < 64; o <<= 1) s += __shfl_xor(s, o, 64);
    float inv = 1.0f / s;
    float4 mm = *(const float4*)(memory + base);
    float4 o4;
    o4.x = e0 * inv * mm.x;
    o4.y = e1 * inv * mm.y;
    o4.z = e2 * inv * mm.z;
    o4.w = e3 * inv * mm.w;
    *(float4*)(out + ((size_t)qi * NK + k) * ND + (size_t)lane * 4) = o4;
  }
}

// ---------------------------------------------------------------------------
extern "C" void kernel_launch(void* const* d_in, const int* in_sizes, int n_in,
                              void* d_out, int out_size, void* d_ws, size_t ws_size,
                              hipStream_t stream) {
  (void)in_sizes; (void)n_in; (void)out_size; (void)ws_size;
  const float* memory   = (const float*)d_in[0];
  const float* mem_coor = (const float*)d_in[1];
  const float* q_coor   = (const float*)d_in[2];
  const float* Wq1 = (const float*)d_in[3];
  const float* bq1 = (const float*)d_in[4];
  const float* Wq2 = (const float*)d_in[5];
  const float* bq2 = (const float*)d_in[6];
  const float* Wk1 = (const float*)d_in[7];
  const float* bk1 = (const float*)d_in[8];
  const float* Wk2 = (const float*)d_in[9];
  const float* bk2 = (const float*)d_in[10];

  // workspace: query (16.8 MB) | kv_pe (33.6 MB) | idx (1 MB)
  float* query = (float*)d_ws;
  float* kv_pe = query + (size_t)NB * NS * ND;
  int*   nidx  = (int*)(kv_pe + (size_t)NB * NL * ND);
  float* outp  = (float*)d_out;

  hipLaunchKernelGGL(mlp_kernel, dim3(NB * NS / 16), dim3(128), 0, stream,
                     q_coor, Wq1, bq1, Wq2, bq2, (const float*)nullptr, query);
  hipLaunchKernelGGL(mlp_kernel, dim3(NB * NL / 16), dim3(128), 0, stream,
                     mem_coor, Wk1, bk1, Wk2, bk2, memory, kv_pe);
  hipLaunchKernelGGL(topk_kernel, dim3(NB * NS / 4), dim3(256), 0, stream,
                     q_coor, mem_coor, nidx);
  hipLaunchKernelGGL(attn_kernel, dim3(NB * NS / 4), dim3(256), 0, stream,
                     query, kv_pe, memory, nidx, outp);
}

// Round 5
// 682.468 us; speedup vs baseline: 1.2449x; 1.2449x over previous
//
#include <hip/hip_runtime.h>
#include <math.h>

// Problem constants (fixed by setup_inputs)
#define NB 4
#define NS 4096
#define NL 8192
#define ND 256
#define NP2 128
#define NK 16

// ---------------------------------------------------------------------------
// Reference-matching fp32 distance metric (XLA/BLAS k=2 GEMM model) — VERIFIED
// in R4 (absmax 6.1e-5). DO NOT CHANGE THE BITS:
//   q2 = fl(qx^2) + fl(qy^2)         m2 likewise      (no FMA)
//   dot = fma(qy, my, fl(qx*mx))                      (GEMM k-loop)
//   d2 = fl(fl(q2 + m2) - 2*dot)                      (no contraction)
// ---------------------------------------------------------------------------
__device__ __forceinline__ float sum_sq_np(float x, float y) {
#pragma clang fp contract(off)
  return x * x + y * y;
}

__device__ __forceinline__ float dist2_ref(float q2, float m2, float qx, float qy,
                                           float mx, float my) {
#pragma clang fp contract(off)
  float dot = __builtin_fmaf(qy, my, qx * mx);
  float s = q2 + m2;
  return s - 2.0f * dot;
}

// float -> order-preserving uint (ascending float => ascending uint)
__device__ __forceinline__ unsigned f32ord(float f) {
  unsigned u = __float_as_uint(f);
  return u ^ ((unsigned)((int)u >> 31) | 0x80000000u);
}

// ---------------------------------------------------------------------------
// Kernel 1: rows of posemb(coor) -> relu(pe@W1+b1)@W2+b2 (+ optional memory)
// 16 rows per block, 128 threads; thread owns output cols (tid, tid+128).
// R5 changes vs R4 (arithmetic sequence identical => bit-identical output):
//  - LDS leading dim padded 16 -> 20 floats (80 B, float4-aligned) to kill
//    stride-16 bank conflicts (R4: SQ_LDS_BANK_CONFLICT = 8.0M).
//  - k-loop unrolled by 8 with batched weight preloads: 16 global loads in
//    flight per wave to hide ~200-cyc L2 latency (R4: VALUBusy 28.6%).
// ---------------------------------------------------------------------------
#define RPAD 20

struct __align__(16) MlpSmem {
  float pe[NP2][RPAD];  // 10.24 KB
  float h[ND][RPAD];    // 20.48 KB
};

__device__ __forceinline__ void fma16(float* acc, float wt, const float4& p0,
                                      const float4& p1, const float4& p2,
                                      const float4& p3) {
  acc[0] = fmaf(p0.x, wt, acc[0]);   acc[1] = fmaf(p0.y, wt, acc[1]);
  acc[2] = fmaf(p0.z, wt, acc[2]);   acc[3] = fmaf(p0.w, wt, acc[3]);
  acc[4] = fmaf(p1.x, wt, acc[4]);   acc[5] = fmaf(p1.y, wt, acc[5]);
  acc[6] = fmaf(p1.z, wt, acc[6]);   acc[7] = fmaf(p1.w, wt, acc[7]);
  acc[8] = fmaf(p2.x, wt, acc[8]);   acc[9] = fmaf(p2.y, wt, acc[9]);
  acc[10] = fmaf(p2.z, wt, acc[10]); acc[11] = fmaf(p2.w, wt, acc[11]);
  acc[12] = fmaf(p3.x, wt, acc[12]); acc[13] = fmaf(p3.y, wt, acc[13]);
  acc[14] = fmaf(p3.z, wt, acc[14]); acc[15] = fmaf(p3.w, wt, acc[15]);
}

__global__ __launch_bounds__(128) void mlp_kernel(
    const float* __restrict__ coor, const float* __restrict__ W1,
    const float* __restrict__ b1, const float* __restrict__ W2,
    const float* __restrict__ b2, const float* __restrict__ addmem,
    float* __restrict__ out) {
  __shared__ MlpSmem sm;
  const int tid = threadIdx.x;
  const int row0 = blockIdx.x * 16;

  // ---- phase 1: PETR 2D sine embedding, transposed into LDS ----
#pragma unroll
  for (int it = 0; it < 8; ++it) {
    int e = tid + it * 128;     // 0..1023 = 16 rows * 2 parts * 32 j
    int r = e >> 6;
    int rem = e & 63;
    int part = rem >> 5;        // 0 -> y, 1 -> x
    int j = rem & 31;
    float c = coor[(size_t)(row0 + r) * 2 + (part ^ 1)];
    float inv_t = exp2f((float)j * -0.4152410118609718f);  // 10000^(-j/32)
    float arg = c * 6.2831853071795864f * inv_t;
    float sv, cv;
    sincosf(arg, &sv, &cv);
    int k0 = part * 64 + 2 * j;
    sm.pe[k0][r] = sv;
    sm.pe[k0 + 1][r] = cv;
  }
  __syncthreads();

  // ---- phase 2: hidden = relu(pe @ W1 + b1) ----
  float acc0[16], acc1[16];
  {
    float bb0 = b1[tid], bb1 = b1[tid + 128];
#pragma unroll
    for (int r = 0; r < 16; ++r) { acc0[r] = bb0; acc1[r] = bb1; }
  }
  for (int k0 = 0; k0 < NP2; k0 += 8) {
    float w0[8], w1[8];
#pragma unroll
    for (int u = 0; u < 8; ++u) {
      w0[u] = W1[(size_t)(k0 + u) * ND + tid];
      w1[u] = W1[(size_t)(k0 + u) * ND + 128 + tid];
    }
#pragma unroll
    for (int u = 0; u < 8; ++u) {
      int k = k0 + u;
      float4 p0 = *(const float4*)&sm.pe[k][0];
      float4 p1 = *(const float4*)&sm.pe[k][4];
      float4 p2 = *(const float4*)&sm.pe[k][8];
      float4 p3 = *(const float4*)&sm.pe[k][12];
      fma16(acc0, w0[u], p0, p1, p2, p3);
      fma16(acc1, w1[u], p0, p1, p2, p3);
    }
  }
#pragma unroll
  for (int r = 0; r < 16; ++r) {
    sm.h[tid][r] = fmaxf(acc0[r], 0.0f);
    sm.h[tid + 128][r] = fmaxf(acc1[r], 0.0f);
  }
  __syncthreads();

  // ---- phase 3: out = h @ W2 + b2 (+ memory) ----
  {
    float bb0 = b2[tid], bb1 = b2[tid + 128];
#pragma unroll
    for (int r = 0; r < 16; ++r) { acc0[r] = bb0; acc1[r] = bb1; }
  }
  for (int k0 = 0; k0 < ND; k0 += 8) {
    float w0[8], w1[8];
#pragma unroll
    for (int u = 0; u < 8; ++u) {
      w0[u] = W2[(size_t)(k0 + u) * ND + tid];
      w1[u] = W2[(size_t)(k0 + u) * ND + 128 + tid];
    }
#pragma unroll
    for (int u = 0; u < 8; ++u) {
      int k = k0 + u;
      float4 h0 = *(const float4*)&sm.h[k][0];
      float4 h1 = *(const float4*)&sm.h[k][4];
      float4 h2 = *(const float4*)&sm.h[k][8];
      float4 h3 = *(const float4*)&sm.h[k][12];
      fma16(acc0, w0[u], h0, h1, h2, h3);
      fma16(acc1, w1[u], h0, h1, h2, h3);
    }
  }
#pragma unroll
  for (int r = 0; r < 16; ++r) {
    size_t g = (size_t)(row0 + r);
    float v0 = acc0[r], v1 = acc1[r];
    if (addmem) {
      v0 += addmem[g * ND + tid];
      v1 += addmem[g * ND + 128 + tid];
    }
    out[g * ND + tid] = v0;
    out[g * ND + 128 + tid] = v1;
  }
}

// ---------------------------------------------------------------------------
// Kernel 2: exact top-16 NN per query under dist2_ref fp32 bits (ties by
// lower index). 4 waves/block, one query per wave.
// R5: no LDS staging of mem_coor (64 KB/batch is L1/L2-resident and shared by
// all waves) => zero barriers; unroll 8 => 8 b64 loads in flight per wave.
// Same point-visit arithmetic => same d2 bits, same tau, same result.
// ---------------------------------------------------------------------------
__global__ __launch_bounds__(256) void topk_kernel(
    const float* __restrict__ q_coor, const float* __restrict__ mem_coor,
    int* __restrict__ idx_out) {
  __shared__ unsigned long long cand[4][256];  // 8 KB
  __shared__ int cnt[4];

  const int tid = threadIdx.x;
  const int wv = tid >> 6;
  const int lane = tid & 63;
  const int qi = blockIdx.x * 4 + wv;  // b*S + s
  const int b = qi >> 12;              // / NS

  const float qx = q_coor[(size_t)qi * 2 + 0];
  const float qy = q_coor[(size_t)qi * 2 + 1];
  const float q2 = sum_sq_np(qx, qy);
  const float2* mc = (const float2*)mem_coor + (size_t)b * NL;

  // ---- phase 1: per-lane minima under the reference metric ----
  float lmin = __builtin_inff();
#pragma unroll 8
  for (int it = 0; it < NL / 64; ++it) {
    float2 c = mc[it * 64 + lane];
    float m2 = sum_sq_np(c.x, c.y);
    float d2 = dist2_ref(q2, m2, qx, qy, c.x, c.y);
    lmin = fminf(lmin, d2);
  }

  // ---- tau = 16th smallest of the 64 lane minima (upper bound on d2_(16);
  // equal minima knocked out together only raise it => still valid) ----
  float tau;
  {
    float cur = lmin;
    for (int r = 0; r < NK; ++r) {
      float m = cur;
#pragma unroll
      for (int o = 1; o < 64; o <<= 1) m = fminf(m, __shfl_xor(m, o, 64));
      tau = m;
      if (cur == m) cur = __builtin_inff();
    }
  }

  // ---- phase 2: compact candidates with d2 <= tau (per-wave, no barrier) --
  if (lane == 0) cnt[wv] = 0;
#pragma unroll 4
  for (int it = 0; it < NL / 64; ++it) {
    int p = it * 64 + lane;
    float2 c = mc[p];
    float m2 = sum_sq_np(c.x, c.y);
    float d2 = dist2_ref(q2, m2, qx, qy, c.x, c.y);
    bool hit = (d2 <= tau);
    unsigned long long mask = __ballot(hit);
    if (mask) {  // wave-uniform branch; usually false
      int base = cnt[wv];
      if (hit) {
        int pos = base + (int)__popcll(mask & ((1ull << lane) - 1ull));
        if (pos < 256) {
          cand[wv][pos] = ((unsigned long long)f32ord(d2) << 32) | (unsigned)p;
        }
      }
      if (lane == 0) cnt[wv] = base + (int)__popcll(mask);
    }
  }

  // ---- phase 3: 16 rounds of wave-wide u64 min (d2 asc, ties idx asc) ----
  int N = cnt[wv];
  if (N > 256) N = 256;
  unsigned long long myc[4];
#pragma unroll
  for (int j = 0; j < 4; ++j) {
    int p = lane + j * 64;
    myc[j] = (p < N) ? cand[wv][p] : ~0ull;
  }
#pragma unroll 1
  for (int r = 0; r < NK; ++r) {
    unsigned long long m01 = myc[0] < myc[1] ? myc[0] : myc[1];
    unsigned long long m23 = myc[2] < myc[3] ? myc[2] : myc[3];
    unsigned long long m = m01 < m23 ? m01 : m23;
#pragma unroll
    for (int o = 1; o < 64; o <<= 1) {
      unsigned long long other = __shfl_xor(m, o, 64);
      if (other < m) m = other;
    }
    if (lane == 0) idx_out[(size_t)qi * NK + r] = (int)(unsigned)(m & 0xffffffffull);
#pragma unroll
    for (int j = 0; j < 4; ++j)
      if (myc[j] == m) myc[j] = ~0ull;
  }
}

// ---------------------------------------------------------------------------
// Kernel 3: gather + per-(b,s,k) softmax over D + scale by memory.
// One wave per (b,s); 4 features per lane; wave shuffle reductions.
// R5: unroll 2 over k (independent iterations) for 2x memory-level parallelism.
// ---------------------------------------------------------------------------
__global__ __launch_bounds__(256) void attn_kernel(
    const float* __restrict__ query, const float* __restrict__ kv_pe,
    const float* __restrict__ memory, const int* __restrict__ idx,
    float* __restrict__ out) {
  const int tid = threadIdx.x;
  const int wv = tid >> 6;
  const int lane = tid & 63;
  const int qi = blockIdx.x * 4 + wv;  // b*S + s
  const int b = qi >> 12;

  float4 q4 = *(const float4*)(query + (size_t)qi * ND + lane * 4);

#pragma unroll 2
  for (int k = 0; k < NK; ++k) {
    int l = idx[(size_t)qi * NK + k];
    size_t base = ((size_t)b * NL + l) * ND + (size_t)lane * 4;
    float4 kv = *(const float4*)(kv_pe + base);
    // prod = query * kv_pe / sqrt(256); /16 is exact so *0.0625f matches bits
    float p0 = q4.x * kv.x * 0.0625f;
    float p1 = q4.y * kv.y * 0.0625f;
    float p2 = q4.z * kv.z * 0.0625f;
    float p3 = q4.w * kv.w * 0.0625f;
    float mx = fmaxf(fmaxf(p0, p1), fmaxf(p2, p3));
#pragma unroll
    for (int o = 1; o < 64; o <<= 1) mx = fmaxf(mx, __shfl_xor(mx, o, 64));
    float e0 = expf(p0 - mx);
    float e1 = expf(p1 - mx);
    float e2 = expf(p2 - mx);
    float e3 = expf(p3 - mx);
    float s = (e0 + e1) + (e2 + e3);
#pragma unroll
    for (int o = 1; o < 64; o <<= 1) s += __shfl_xor(s, o, 64);
    float inv = 1.0f / s;
    float4 mm = *(const float4*)(memory + base);
    float4 o4;
    o4.x = e0 * inv * mm.x;
    o4.y = e1 * inv * mm.y;
    o4.z = e2 * inv * mm.z;
    o4.w = e3 * inv * mm.w;
    *(float4*)(out + ((size_t)qi * NK + k) * ND + (size_t)lane * 4) = o4;
  }
}

// ---------------------------------------------------------------------------
extern "C" void kernel_launch(void* const* d_in, const int* in_sizes, int n_in,
                              void* d_out, int out_size, void* d_ws, size_t ws_size,
                              hipStream_t stream) {
  (void)in_sizes; (void)n_in; (void)out_size; (void)ws_size;
  const float* memory   = (const float*)d_in[0];
  const float* mem_coor = (const float*)d_in[1];
  const float* q_coor   = (const float*)d_in[2];
  const float* Wq1 = (const float*)d_in[3];
  const float* bq1 = (const float*)d_in[4];
  const float* Wq2 = (const float*)d_in[5];
  const float* bq2 = (const float*)d_in[6];
  const float* Wk1 = (const float*)d_in[7];
  const float* bk1 = (const float*)d_in[8];
  const float* Wk2 = (const float*)d_in[9];
  const float* bk2 = (const float*)d_in[10];

  // workspace: query (16.8 MB) | kv_pe (33.6 MB) | idx (1 MB)
  float* query = (float*)d_ws;
  float* kv_pe = query + (size_t)NB * NS * ND;
  int*   nidx  = (int*)(kv_pe + (size_t)NB * NL * ND);
  float* outp  = (float*)d_out;

  hipLaunchKernelGGL(mlp_kernel, dim3(NB * NS / 16), dim3(128), 0, stream,
                     q_coor, Wq1, bq1, Wq2, bq2, (const float*)nullptr, query);
  hipLaunchKernelGGL(mlp_kernel, dim3(NB * NL / 16), dim3(128), 0, stream,
                     mem_coor, Wk1, bk1, Wk2, bk2, memory, kv_pe);
  hipLaunchKernelGGL(topk_kernel, dim3(NB * NS / 4), dim3(256), 0, stream,
                     q_coor, mem_coor, nidx);
  hipLaunchKernelGGL(attn_kernel, dim3(NB * NS / 4), dim3(256), 0, stream,
                     query, kv_pe, memory, nidx, outp);
}